// Round 1
// baseline (208.655 us; speedup 1.0000x reference)
//
#include <hip/hip_runtime.h>

// MultiHeadAttentionForViTDiscriminator: B=4, C=1024, D=1024, H=16, DH=64
// Pipeline (all fp16 internal, fp32 accum via MFMA):
//   cvt W's -> cvt Xq -> proj q -> cvt Xk -> proj k -> cvt Xv -> proj v
//   -> transpose v -> attention (dist-softmax, flash-style, no max needed)
//   -> final proj + bias (fp32 out)
// Workspace layout (48 MB assumed available):
//   [0,8M)   W16: Wq,Wk,Wv,Wp   (4 x 1M f16)
//   [8,16M)  Xbuf (reused: Xq/Xk/Xv f16, then attn_out f16)
//   [16,24M) qb   [24,32M) kb   [32,40M) vb   [40,48M) vT

typedef _Float16 f16;
typedef __attribute__((ext_vector_type(8))) _Float16 f16x8;
typedef __attribute__((ext_vector_type(4))) float f32x4;

#define MFMA16(a, b, c) __builtin_amdgcn_mfma_f32_16x16x32_f16((a), (b), (c), 0, 0, 0)

__global__ __launch_bounds__(256) void cvt_w4(const float* __restrict__ s0,
                                              const float* __restrict__ s1,
                                              const float* __restrict__ s2,
                                              const float* __restrict__ s3,
                                              f16* __restrict__ dst) {
    const float* src = (blockIdx.y == 0) ? s0 : (blockIdx.y == 1) ? s1 : (blockIdx.y == 2) ? s2 : s3;
    f16* d = dst + (size_t)blockIdx.y * (1u << 20);
    int i = (blockIdx.x * 256 + threadIdx.x) * 8;  // 512 blocks * 256 * 8 = 1M
    float4 a = *(const float4*)(src + i);
    float4 b = *(const float4*)(src + i + 4);
    f16x8 o;
    o[0] = (f16)a.x; o[1] = (f16)a.y; o[2] = (f16)a.z; o[3] = (f16)a.w;
    o[4] = (f16)b.x; o[5] = (f16)b.y; o[6] = (f16)b.z; o[7] = (f16)b.w;
    *(f16x8*)(d + i) = o;
}

__global__ __launch_bounds__(256) void cvt_x(const float* __restrict__ src, f16* __restrict__ dst) {
    int i = (blockIdx.x * 256 + threadIdx.x) * 8;  // 2048 blocks * 256 * 8 = 4M
    float4 a = *(const float4*)(src + i);
    float4 b = *(const float4*)(src + i + 4);
    f16x8 o;
    o[0] = (f16)a.x; o[1] = (f16)a.y; o[2] = (f16)a.z; o[3] = (f16)a.w;
    o[4] = (f16)b.x; o[5] = (f16)b.y; o[6] = (f16)b.z; o[7] = (f16)b.w;
    *(f16x8*)(dst + i) = o;
}

// C[M,N] = A[M,K] * Bw[N,K]^T.  MODE 0: f16 out.  MODE 1: f32 out + bias.
template <int MODE>
__global__ __launch_bounds__(256) void gemm_bt(const f16* __restrict__ A,
                                               const f16* __restrict__ Bw,
                                               f16* __restrict__ Co,
                                               float* __restrict__ Cf,
                                               const float* __restrict__ bias,
                                               int M, int N, int K) {
    __shared__ __attribute__((aligned(16))) f16 As[128][72];  // +8 pad: row stride 144B
    __shared__ __attribute__((aligned(16))) f16 Bs[128][72];
    const int tid = threadIdx.x;
    const int lane = tid & 63;
    const int w = tid >> 6;
    const int wr = (w >> 1) * 64, wc = (w & 1) * 64;
    const int l15 = lane & 15, l4 = lane >> 4;
    const int row0 = blockIdx.y * 128, col0 = blockIdx.x * 128;
    const int sr = tid >> 3, sc = (tid & 7) * 8;

    f32x4 acc[4][4] = {};

    for (int kt = 0; kt < K; kt += 64) {
        __syncthreads();
#pragma unroll
        for (int i = 0; i < 4; ++i) {
            int r = sr + i * 32;
            *(f16x8*)&As[r][sc] = *(const f16x8*)&A[(size_t)(row0 + r) * K + kt + sc];
            *(f16x8*)&Bs[r][sc] = *(const f16x8*)&Bw[(size_t)(col0 + r) * K + kt + sc];
        }
        __syncthreads();
#pragma unroll
        for (int ks = 0; ks < 2; ++ks) {
            f16x8 af[4], bf[4];
#pragma unroll
            for (int m = 0; m < 4; ++m) af[m] = *(const f16x8*)&As[wr + m * 16 + l15][ks * 32 + l4 * 8];
#pragma unroll
            for (int n = 0; n < 4; ++n) bf[n] = *(const f16x8*)&Bs[wc + n * 16 + l15][ks * 32 + l4 * 8];
#pragma unroll
            for (int m = 0; m < 4; ++m)
#pragma unroll
                for (int n = 0; n < 4; ++n) acc[m][n] = MFMA16(af[m], bf[n], acc[m][n]);
        }
    }

#pragma unroll
    for (int m = 0; m < 4; ++m)
#pragma unroll
        for (int n = 0; n < 4; ++n)
#pragma unroll
            for (int r = 0; r < 4; ++r) {
                int rr = row0 + wr + m * 16 + l4 * 4 + r;
                int cc = col0 + wc + n * 16 + l15;
                if (MODE == 0)
                    Co[(size_t)rr * N + cc] = (f16)acc[m][n][r];
                else
                    Cf[(size_t)rr * N + cc] = acc[m][n][r] + bias[cc];
            }
}

// v (4096 tokens x 1024) -> vT[b*16+h][dh=64][c=1024]
__global__ __launch_bounds__(256) void transpose_v(const f16* __restrict__ v, f16* __restrict__ vT) {
    __shared__ __attribute__((aligned(16))) f16 T[64][72];
    const int bh = blockIdx.y;
    const int b = bh >> 4, h = bh & 15;
    const int ct = blockIdx.x * 64;
    const int tid = threadIdx.x;
    const int cl = tid >> 3, d0 = (tid & 7) * 8;
#pragma unroll
    for (int i = 0; i < 2; ++i) {
        int c = cl + i * 32;
        *(f16x8*)&T[c][d0] = *(const f16x8*)&v[(size_t)(b * 1024 + ct + c) * 1024 + h * 64 + d0];
    }
    __syncthreads();
    const int dl = tid >> 3, c0 = (tid & 7) * 8;
#pragma unroll
    for (int i = 0; i < 2; ++i) {
        int d = dl + i * 32;
        f16x8 o;
#pragma unroll
        for (int j = 0; j < 8; ++j) o[j] = T[c0 + j][d];
        *(f16x8*)&vT[(size_t)(bh * 64 + d) * 1024 + ct + c0] = o;
    }
}

// Distance attention. grid (8 q-tiles, 64 bh), 256 threads (4 waves x 32 q-rows).
__global__ __launch_bounds__(256) void attn(const f16* __restrict__ qb,
                                            const f16* __restrict__ kb,
                                            const f16* __restrict__ vT,
                                            f16* __restrict__ out) {
    __shared__ __attribute__((aligned(16))) f16 Ks[128][72];
    __shared__ __attribute__((aligned(16))) f16 Ps[128][136];
    const int tid = threadIdx.x;
    const int lane = tid & 63;
    const int w = tid >> 6;
    const int l15 = lane & 15, l4 = lane >> 4;
    const int bh = blockIdx.y, b = bh >> 4, h = bh & 15;
    const int qt = blockIdx.x;
    const int wq = w * 32;
    const int hcol = h * 64;
    const int qrow0 = b * 1024 + qt * 128;
    const f16* vTh = vT + (size_t)bh * 64 * 1024;

    // Q fragments in registers (reused across all 8 K-tiles)
    f16x8 aq[2][2];
#pragma unroll
    for (int m = 0; m < 2; ++m)
#pragma unroll
        for (int ks = 0; ks < 2; ++ks)
            aq[m][ks] = *(const f16x8*)&qb[(size_t)(qrow0 + wq + m * 16 + l15) * 1024 + hcol + ks * 32 + l4 * 8];

    // q2 row norms, redistributed to D-layout indexing (row = l4*4+r)
    float q2r[2][4];
#pragma unroll
    for (int m = 0; m < 2; ++m) {
        float s = 0.f;
#pragma unroll
        for (int ks = 0; ks < 2; ++ks)
#pragma unroll
            for (int j = 0; j < 8; ++j) {
                float x = (float)aq[m][ks][j];
                s += x * x;
            }
        s += __shfl_xor(s, 16);
        s += __shfl_xor(s, 32);  // all lanes: q2 of row wq+m*16+l15
#pragma unroll
        for (int r = 0; r < 4; ++r) q2r[m][r] = __shfl(s, l4 * 4 + r, 16);
    }

    f32x4 accv[2][4] = {};
    float den[2][4] = {{0.f, 0.f, 0.f, 0.f}, {0.f, 0.f, 0.f, 0.f}};
    const float scale = 0.125f;  // DH^-0.5
    const int sr = tid >> 3, sc0 = (tid & 7) * 8;

    for (int kt = 0; kt < 8; ++kt) {
        __syncthreads();
#pragma unroll
        for (int i = 0; i < 4; ++i) {
            int r = sr + i * 32;
            *(f16x8*)&Ks[r][sc0] = *(const f16x8*)&kb[(size_t)(b * 1024 + kt * 128 + r) * 1024 + hcol + sc0];
        }
        __syncthreads();

        // S = Q K^T, transform to p = exp(sqrt(relu(q2+k2-2S))*scale)
#pragma unroll
        for (int n = 0; n < 8; ++n) {
            f16x8 bk0 = *(const f16x8*)&Ks[n * 16 + l15][l4 * 8];
            f16x8 bk1 = *(const f16x8*)&Ks[n * 16 + l15][32 + l4 * 8];
            float k2 = 0.f;
#pragma unroll
            for (int j = 0; j < 8; ++j) {
                float x0 = (float)bk0[j], x1 = (float)bk1[j];
                k2 += x0 * x0 + x1 * x1;
            }
            k2 += __shfl_xor(k2, 16);
            k2 += __shfl_xor(k2, 32);  // k2 of key row n*16+l15 (lane-local for this n)
#pragma unroll
            for (int m = 0; m < 2; ++m) {
                f32x4 z = {0.f, 0.f, 0.f, 0.f};
                f32x4 sfr = MFMA16(aq[m][0], bk0, z);
                sfr = MFMA16(aq[m][1], bk1, sfr);
#pragma unroll
                for (int r = 0; r < 4; ++r) {
                    float sv = q2r[m][r] + k2 - 2.0f * sfr[r];
                    float wv = sqrtf(fmaxf(sv, 0.0f)) * scale;
                    float p = __expf(wv);  // bounded by ~e^1.5: no max-subtraction needed
                    den[m][r] += p;
                    Ps[wq + m * 16 + l4 * 4 + r][n * 16 + l15] = (f16)p;
                }
            }
        }

        // PV: num += P * V   (P rows are wave-private; no barrier needed)
        f16x8 ap[2][4];
#pragma unroll
        for (int m = 0; m < 2; ++m)
#pragma unroll
            for (int kk = 0; kk < 4; ++kk)
                ap[m][kk] = *(const f16x8*)&Ps[wq + m * 16 + l15][kk * 32 + l4 * 8];
#pragma unroll
        for (int n2 = 0; n2 < 4; ++n2) {
            f16x8 bv[4];
#pragma unroll
            for (int kk = 0; kk < 4; ++kk)
                bv[kk] = *(const f16x8*)&vTh[(size_t)(n2 * 16 + l15) * 1024 + kt * 128 + kk * 32 + l4 * 8];
#pragma unroll
            for (int m = 0; m < 2; ++m)
#pragma unroll
                for (int kk = 0; kk < 4; ++kk) accv[m][n2] = MFMA16(ap[m][kk], bv[kk], accv[m][n2]);
        }
    }

    // full row-sum of den across the 16 col-lanes, then normalize + store
#pragma unroll
    for (int m = 0; m < 2; ++m)
#pragma unroll
        for (int r = 0; r < 4; ++r) {
            float d = den[m][r];
            d += __shfl_xor(d, 1);
            d += __shfl_xor(d, 2);
            d += __shfl_xor(d, 4);
            d += __shfl_xor(d, 8);
            den[m][r] = 1.0f / d;
        }
#pragma unroll
    for (int m = 0; m < 2; ++m)
#pragma unroll
        for (int n2 = 0; n2 < 4; ++n2)
#pragma unroll
            for (int r = 0; r < 4; ++r)
                out[(size_t)(qrow0 + wq + m * 16 + l4 * 4 + r) * 1024 + hcol + n2 * 16 + l15] =
                    (f16)(accv[m][n2][r] * den[m][r]);
}

extern "C" void kernel_launch(void* const* d_in, const int* in_sizes, int n_in,
                              void* d_out, int out_size, void* d_ws, size_t ws_size,
                              hipStream_t stream) {
    const float* Xq = (const float*)d_in[0];
    const float* Xk = (const float*)d_in[1];
    const float* Xv = (const float*)d_in[2];
    const float* Wq = (const float*)d_in[3];
    const float* Wk = (const float*)d_in[4];
    const float* Wv = (const float*)d_in[5];
    const float* Wp = (const float*)d_in[6];
    const float* bp = (const float*)d_in[7];
    float* out = (float*)d_out;

    char* ws = (char*)d_ws;
    f16* W16 = (f16*)(ws);                     // 4 x 1M f16
    f16* Xbuf = (f16*)(ws + (8ull << 20));     // X conv / attn out
    f16* qb = (f16*)(ws + (16ull << 20));
    f16* kb = (f16*)(ws + (24ull << 20));
    f16* vb = (f16*)(ws + (32ull << 20));
    f16* vTb = (f16*)(ws + (40ull << 20));

    const int M = 4096, N = 1024, K = 1024;
    dim3 gg(N / 128, M / 128);

    cvt_w4<<<dim3(512, 4), 256, 0, stream>>>(Wq, Wk, Wv, Wp, W16);

    cvt_x<<<2048, 256, 0, stream>>>(Xq, Xbuf);
    gemm_bt<0><<<gg, 256, 0, stream>>>(Xbuf, W16 + 0 * (1u << 20), qb, nullptr, nullptr, M, N, K);
    cvt_x<<<2048, 256, 0, stream>>>(Xk, Xbuf);
    gemm_bt<0><<<gg, 256, 0, stream>>>(Xbuf, W16 + 1 * (1u << 20), kb, nullptr, nullptr, M, N, K);
    cvt_x<<<2048, 256, 0, stream>>>(Xv, Xbuf);
    gemm_bt<0><<<gg, 256, 0, stream>>>(Xbuf, W16 + 2 * (1u << 20), vb, nullptr, nullptr, M, N, K);

    transpose_v<<<dim3(16, 64), 256, 0, stream>>>(vb, vTb);
    attn<<<dim3(8, 64), 256, 0, stream>>>(qb, kb, vTb, Xbuf);

    gemm_bt<1><<<gg, 256, 0, stream>>>(Xbuf, W16 + 3 * (1u << 20), nullptr, out, bp, M, N, K);
}

// Round 2
// 197.460 us; speedup vs baseline: 1.0567x; 1.0567x over previous
//
#include <hip/hip_runtime.h>

// MultiHeadAttentionForViTDiscriminator: B=4, C=1024, D=1024, H=16, DH=64
// Pipeline (fp16 internal, fp32 accum via MFMA):
//   cvt W -> [cvt X -> proj] x3 (q proj pre-scaled by -2*c'^2)
//   -> norms (q2*c'^2, k2*c'^2) -> transpose v
//   -> attention: S'' = mfma(qs, k, C0=q2+k2); p = exp2(sqrt(relu(S'')))
//   -> final proj + bias (fp32 out)
// where c' = DH^-0.5 * log2(e), so exp2(sqrt(c'^2 * dist^2)) = exp(dist/8).
// Workspace (48 MB):
//   [0,8M)   W16: Wq,Wk,Wv,Wp (4 x 2MB f16).  After k-gemm, the Wq slot's
//            first 512KB is reused for q2c2/k2c2 (rewritten by cvt_w4 each call).
//   [8,16M)  Xbuf (Xq/Xk/Xv f16 conversions, then attn out)
//   [16,24M) qb (pre-scaled)  [24,32M) kb  [32,40M) vb  [40,48M) vT

typedef _Float16 f16;
typedef __attribute__((ext_vector_type(2))) _Float16 f16x2;
typedef __attribute__((ext_vector_type(8))) _Float16 f16x8;
typedef __attribute__((ext_vector_type(4))) float f32x4;

#define MFMA16(a, b, c) __builtin_amdgcn_mfma_f32_16x16x32_f16((a), (b), (c), 0, 0, 0)

constexpr double LOG2E = 1.4426950408889634;
constexpr double C2d = 0.015625 * LOG2E * LOG2E;  // (DH^-0.5 * log2e)^2

#if __has_builtin(__builtin_amdgcn_exp2f)
#define EXP2F(x) __builtin_amdgcn_exp2f(x)
#else
#define EXP2F(x) exp2f(x)
#endif
#if __has_builtin(__builtin_amdgcn_sqrtf)
#define SQRTF(x) __builtin_amdgcn_sqrtf(x)
#else
#define SQRTF(x) sqrtf(x)
#endif

__global__ __launch_bounds__(256) void cvt_w4(const float* __restrict__ s0,
                                              const float* __restrict__ s1,
                                              const float* __restrict__ s2,
                                              const float* __restrict__ s3,
                                              f16* __restrict__ dst) {
    const float* src = (blockIdx.y == 0) ? s0 : (blockIdx.y == 1) ? s1 : (blockIdx.y == 2) ? s2 : s3;
    f16* d = dst + (size_t)blockIdx.y * (1u << 20);
    int i = (blockIdx.x * 256 + threadIdx.x) * 8;
    float4 a = *(const float4*)(src + i);
    float4 b = *(const float4*)(src + i + 4);
    f16x8 o;
    o[0] = (f16)a.x; o[1] = (f16)a.y; o[2] = (f16)a.z; o[3] = (f16)a.w;
    o[4] = (f16)b.x; o[5] = (f16)b.y; o[6] = (f16)b.z; o[7] = (f16)b.w;
    *(f16x8*)(d + i) = o;
}

__global__ __launch_bounds__(256) void cvt_x(const float* __restrict__ src, f16* __restrict__ dst) {
    int i = (blockIdx.x * 256 + threadIdx.x) * 8;
    float4 a = *(const float4*)(src + i);
    float4 b = *(const float4*)(src + i + 4);
    f16x8 o;
    o[0] = (f16)a.x; o[1] = (f16)a.y; o[2] = (f16)a.z; o[3] = (f16)a.w;
    o[4] = (f16)b.x; o[5] = (f16)b.y; o[6] = (f16)b.z; o[7] = (f16)b.w;
    *(f16x8*)(dst + i) = o;
}

// C[M,N] = (A[M,K] * Bw[N,K]^T) * oscale.  MODE 0: f16 out.  MODE 1: f32 out + bias.
template <int MODE>
__global__ __launch_bounds__(256) void gemm_bt(const f16* __restrict__ A,
                                               const f16* __restrict__ Bw,
                                               f16* __restrict__ Co,
                                               float* __restrict__ Cf,
                                               const float* __restrict__ bias,
                                               float oscale,
                                               int M, int N, int K) {
    __shared__ __attribute__((aligned(16))) f16 As[128][72];
    __shared__ __attribute__((aligned(16))) f16 Bs[128][72];
    const int tid = threadIdx.x;
    const int lane = tid & 63;
    const int w = tid >> 6;
    const int wr = (w >> 1) * 64, wc = (w & 1) * 64;
    const int l15 = lane & 15, l4 = lane >> 4;
    const int row0 = blockIdx.y * 128, col0 = blockIdx.x * 128;
    const int sr = tid >> 3, sc = (tid & 7) * 8;

    f32x4 acc[4][4] = {};

    for (int kt = 0; kt < K; kt += 64) {
        __syncthreads();
#pragma unroll
        for (int i = 0; i < 4; ++i) {
            int r = sr + i * 32;
            *(f16x8*)&As[r][sc] = *(const f16x8*)&A[(size_t)(row0 + r) * K + kt + sc];
            *(f16x8*)&Bs[r][sc] = *(const f16x8*)&Bw[(size_t)(col0 + r) * K + kt + sc];
        }
        __syncthreads();
#pragma unroll
        for (int ks = 0; ks < 2; ++ks) {
            f16x8 af[4], bf[4];
#pragma unroll
            for (int m = 0; m < 4; ++m) af[m] = *(const f16x8*)&As[wr + m * 16 + l15][ks * 32 + l4 * 8];
#pragma unroll
            for (int n = 0; n < 4; ++n) bf[n] = *(const f16x8*)&Bs[wc + n * 16 + l15][ks * 32 + l4 * 8];
#pragma unroll
            for (int m = 0; m < 4; ++m)
#pragma unroll
                for (int n = 0; n < 4; ++n) acc[m][n] = MFMA16(af[m], bf[n], acc[m][n]);
        }
    }

#pragma unroll
    for (int m = 0; m < 4; ++m)
#pragma unroll
        for (int n = 0; n < 4; ++n)
#pragma unroll
            for (int r = 0; r < 4; ++r) {
                int rr = row0 + wr + m * 16 + l4 * 4 + r;
                int cc = col0 + wc + n * 16 + l15;
                if (MODE == 0)
                    Co[(size_t)rr * N + cc] = (f16)(acc[m][n][r] * oscale);
                else
                    Cf[(size_t)rr * N + cc] = acc[m][n][r] + bias[cc];
            }
}

// q2c2[(b*16+h)*1024+c] = sum(qs^2)/(4*C2) ; k2c2[...] = sum(k^2)*C2
__global__ __launch_bounds__(256) void norms(const f16* __restrict__ qsb,
                                             const f16* __restrict__ kbb,
                                             float* __restrict__ q2o,
                                             float* __restrict__ k2o) {
    const int idx = blockIdx.x * 256 + threadIdx.x;  // 65536 per side
    const int h = idx >> 12, token = idx & 4095;
    const int side = blockIdx.y;
    const f16* src = side ? kbb : qsb;
    const float scale = side ? (float)C2d : (float)(1.0 / (4.0 * C2d));
    const f16* p = src + (size_t)token * 1024 + h * 64;
    float s = 0.f;
#pragma unroll
    for (int j = 0; j < 8; ++j) {
        f16x8 v = *(const f16x8*)(p + j * 8);
#if __has_builtin(__builtin_amdgcn_fdot2)
#pragma unroll
        for (int t = 0; t < 4; ++t) {
            f16x2 pr = {v[2 * t], v[2 * t + 1]};
            s = __builtin_amdgcn_fdot2(pr, pr, s, false);
        }
#else
#pragma unroll
        for (int t = 0; t < 8; ++t) {
            float x = (float)v[t];
            s += x * x;
        }
#endif
    }
    float* dst = side ? k2o : q2o;
    dst[(size_t)((token >> 10) * 16 + h) * 1024 + (token & 1023)] = s * scale;
}

// v (4096 tokens x 1024) -> vT[b*16+h][dh=64][c=1024]
__global__ __launch_bounds__(256) void transpose_v(const f16* __restrict__ v, f16* __restrict__ vT) {
    __shared__ __attribute__((aligned(16))) f16 T[64][72];
    const int bh = blockIdx.y;
    const int b = bh >> 4, h = bh & 15;
    const int ct = blockIdx.x * 64;
    const int tid = threadIdx.x;
    const int cl = tid >> 3, d0 = (tid & 7) * 8;
#pragma unroll
    for (int i = 0; i < 2; ++i) {
        int c = cl + i * 32;
        *(f16x8*)&T[c][d0] = *(const f16x8*)&v[(size_t)(b * 1024 + ct + c) * 1024 + h * 64 + d0];
    }
    __syncthreads();
    const int dl = tid >> 3, c0 = (tid & 7) * 8;
#pragma unroll
    for (int i = 0; i < 2; ++i) {
        int d = dl + i * 32;
        f16x8 o;
#pragma unroll
        for (int j = 0; j < 8; ++j) o[j] = T[c0 + j][d];
        *(f16x8*)&vT[(size_t)(bh * 64 + d) * 1024 + ct + c0] = o;
    }
}

// Distance attention. grid (16 q-tiles of 64 rows, 64 bh), 256 threads = 4 waves x 16 q-rows.
__global__ __launch_bounds__(256) void attn(const f16* __restrict__ qs,
                                            const f16* __restrict__ kb,
                                            const f16* __restrict__ vT,
                                            const float* __restrict__ q2c2,
                                            const float* __restrict__ k2c2,
                                            f16* __restrict__ out) {
    __shared__ __attribute__((aligned(16))) f16 Ks[128][72];
    __shared__ __attribute__((aligned(16))) f16 Ps[64][136];
    __shared__ float k2tile[128];
    const int tid = threadIdx.x;
    const int lane = tid & 63;
    const int w = tid >> 6;
    const int l15 = lane & 15, l4 = lane >> 4;
    const int bh = blockIdx.y, b = bh >> 4, h = bh & 15;
    const int qt = blockIdx.x;
    const int wq = w * 16;
    const int hcol = h * 64;
    const int qrow0 = b * 1024 + qt * 64;
    const f16* vTh = vT + (size_t)bh * 64 * 1024;

    // Q fragments (A-operand rows = wq + l15), pre-scaled by -2*C2
    f16x8 aq0 = *(const f16x8*)&qs[(size_t)(qrow0 + wq + l15) * 1024 + hcol + l4 * 8];
    f16x8 aq1 = *(const f16x8*)&qs[(size_t)(qrow0 + wq + l15) * 1024 + hcol + 32 + l4 * 8];

    // q2*C2 for this lane's D-rows (row = wq + l4*4 + r)
    float q2r[4];
#pragma unroll
    for (int r = 0; r < 4; ++r) q2r[r] = q2c2[(size_t)bh * 1024 + qt * 64 + wq + l4 * 4 + r];

    f32x4 accv[4] = {};
    float den[4] = {0.f, 0.f, 0.f, 0.f};
    const int sr = tid >> 3, sc0 = (tid & 7) * 8;
    const int rsw = (l15 >> 2) << 4;  // read-side Ps swizzle

    for (int kt = 0; kt < 8; ++kt) {
        __syncthreads();
#pragma unroll
        for (int i = 0; i < 4; ++i) {
            int r = sr + i * 32;
            *(f16x8*)&Ks[r][sc0] = *(const f16x8*)&kb[(size_t)(b * 1024 + kt * 128 + r) * 1024 + hcol + sc0];
        }
        if (tid < 128) k2tile[tid] = k2c2[(size_t)bh * 1024 + kt * 128 + tid];
        __syncthreads();

        // S'' = (q2+k2)*C2 - 2*C2*qk via MFMA C-init; p = exp2(sqrt(relu(S'')))
#pragma unroll
        for (int n = 0; n < 8; ++n) {
            f16x8 bk0 = *(const f16x8*)&Ks[n * 16 + l15][l4 * 8];
            f16x8 bk1 = *(const f16x8*)&Ks[n * 16 + l15][32 + l4 * 8];
            float k2v = k2tile[n * 16 + l15];
            f32x4 c0;
#pragma unroll
            for (int r = 0; r < 4; ++r) c0[r] = q2r[r] + k2v;
            f32x4 sfr = MFMA16(aq0, bk0, c0);
            sfr = MFMA16(aq1, bk1, sfr);
#pragma unroll
            for (int r = 0; r < 4; ++r) {
                float p = EXP2F(SQRTF(fmaxf(sfr[r], 0.f)));
                den[r] += p;
                // store row = wq+l4*4+r; swizzled col: (row>>2)&3 == l4 here
                Ps[wq + l4 * 4 + r][(n * 16 + l15) ^ (l4 << 4)] = (f16)p;
            }
        }

        // PV (P rows are wave-private; no barrier needed)
        f16x8 ap[4];
#pragma unroll
        for (int kk = 0; kk < 4; ++kk)
            ap[kk] = *(const f16x8*)&Ps[wq + l15][(kk * 32 + l4 * 8) ^ rsw];
#pragma unroll
        for (int n2 = 0; n2 < 4; ++n2) {
            f16x8 bv[4];
#pragma unroll
            for (int kk = 0; kk < 4; ++kk)
                bv[kk] = *(const f16x8*)&vTh[(size_t)(n2 * 16 + l15) * 1024 + kt * 128 + kk * 32 + l4 * 8];
#pragma unroll
            for (int kk = 0; kk < 4; ++kk) accv[n2] = MFMA16(ap[kk], bv[kk], accv[n2]);
        }
    }

    // row-sum of den across the 16 col-lanes, normalize, store
#pragma unroll
    for (int r = 0; r < 4; ++r) {
        float d = den[r];
        d += __shfl_xor(d, 1);
        d += __shfl_xor(d, 2);
        d += __shfl_xor(d, 4);
        d += __shfl_xor(d, 8);
        den[r] = 1.0f / d;
    }
#pragma unroll
    for (int n2 = 0; n2 < 4; ++n2)
#pragma unroll
        for (int r = 0; r < 4; ++r)
            out[(size_t)(qrow0 + wq + l4 * 4 + r) * 1024 + hcol + n2 * 16 + l15] =
                (f16)(accv[n2][r] * den[r]);
}

extern "C" void kernel_launch(void* const* d_in, const int* in_sizes, int n_in,
                              void* d_out, int out_size, void* d_ws, size_t ws_size,
                              hipStream_t stream) {
    const float* Xq = (const float*)d_in[0];
    const float* Xk = (const float*)d_in[1];
    const float* Xv = (const float*)d_in[2];
    const float* Wq = (const float*)d_in[3];
    const float* Wk = (const float*)d_in[4];
    const float* Wv = (const float*)d_in[5];
    const float* Wp = (const float*)d_in[6];
    const float* bp = (const float*)d_in[7];
    float* out = (float*)d_out;

    char* ws = (char*)d_ws;
    f16* W16 = (f16*)(ws);
    f16* Xbuf = (f16*)(ws + (8ull << 20));
    f16* qb = (f16*)(ws + (16ull << 20));
    f16* kb = (f16*)(ws + (24ull << 20));
    f16* vb = (f16*)(ws + (32ull << 20));
    f16* vTb = (f16*)(ws + (40ull << 20));
    // q2/k2 buffers overlay the Wq16 slot (dead after the q/k gemms; rewritten
    // by cvt_w4 at the start of every launch -> deterministic).
    float* q2c2 = (float*)(ws);
    float* k2c2 = (float*)(ws + (256ull << 10));

    const int M = 4096, N = 1024, K = 1024;
    dim3 gg(N / 128, M / 128);
    const float qscale = (float)(-2.0 * C2d);

    cvt_w4<<<dim3(512, 4), 256, 0, stream>>>(Wq, Wk, Wv, Wp, W16);

    cvt_x<<<2048, 256, 0, stream>>>(Xq, Xbuf);
    gemm_bt<0><<<gg, 256, 0, stream>>>(Xbuf, W16 + 0 * (1u << 20), qb, nullptr, nullptr, qscale, M, N, K);
    cvt_x<<<2048, 256, 0, stream>>>(Xk, Xbuf);
    gemm_bt<0><<<gg, 256, 0, stream>>>(Xbuf, W16 + 1 * (1u << 20), kb, nullptr, nullptr, 1.0f, M, N, K);

    norms<<<dim3(256, 2), 256, 0, stream>>>(qb, kb, q2c2, k2c2);

    cvt_x<<<2048, 256, 0, stream>>>(Xv, Xbuf);
    gemm_bt<0><<<gg, 256, 0, stream>>>(Xbuf, W16 + 2 * (1u << 20), vb, nullptr, nullptr, 1.0f, M, N, K);

    transpose_v<<<dim3(16, 64), 256, 0, stream>>>(vb, vTb);
    attn<<<dim3(16, 64), 256, 0, stream>>>(qb, kb, vTb, q2c2, k2c2, Xbuf);

    gemm_bt<1><<<gg, 256, 0, stream>>>(Xbuf, W16 + 3 * (1u << 20), nullptr, out, bp, 1.0f, M, N, K);
}

// Round 3
// 158.049 us; speedup vs baseline: 1.3202x; 1.2494x over previous
//
#include <hip/hip_runtime.h>

// MultiHeadAttentionForViTDiscriminator: B=4, C=1024, D=1024, H=16, DH=64
// R3: GEMM -> m97 pattern (global_load_lds w16, BN=64, 2 blocks/CU, XCD swizzle)
//     attn -> 128-row blocks, 32 rows/wave, V in LDS, T14 reg-prefetch, XCD remap
// Workspace (48 MB):
//   [0,8M) W16: Wq,Wk,Wv,Wp (4 x 2MB). Slot 0 reused for q2c2/k2c2 after q/k gemms.
//   [8,16M) Xbuf  [16,24M) qb  [24,32M) kb  [32,40M) vb  [40,48M) vT

typedef _Float16 f16;
typedef __attribute__((ext_vector_type(2))) _Float16 f16x2;
typedef __attribute__((ext_vector_type(8))) _Float16 f16x8;
typedef __attribute__((ext_vector_type(4))) float f32x4;

#define MFMA16(a, b, c) __builtin_amdgcn_mfma_f32_16x16x32_f16((a), (b), (c), 0, 0, 0)

constexpr double LOG2E = 1.4426950408889634;
constexpr double C2d = 0.015625 * LOG2E * LOG2E;  // (DH^-0.5 * log2e)^2

#if __has_builtin(__builtin_amdgcn_exp2f)
#define EXP2F(x) __builtin_amdgcn_exp2f(x)
#else
#define EXP2F(x) exp2f(x)
#endif
#if __has_builtin(__builtin_amdgcn_sqrtf)
#define SQRTF(x) __builtin_amdgcn_sqrtf(x)
#else
#define SQRTF(x) sqrtf(x)
#endif

// Async global->LDS, 16B per lane. Dest: wave-uniform base + lane*16.
__device__ __forceinline__ void stage16(const f16* g, f16* lds_base_uniform) {
#if __has_builtin(__builtin_amdgcn_global_load_lds)
    __builtin_amdgcn_global_load_lds((const __attribute__((address_space(1))) void*)g,
                                     (__attribute__((address_space(3))) void*)lds_base_uniform,
                                     16, 0, 0);
#else
    const int lane = threadIdx.x & 63;
    *(f16x8*)(lds_base_uniform + lane * 8) = *(const f16x8*)g;
#endif
}

__global__ __launch_bounds__(256) void cvt_w4(const float* __restrict__ s0,
                                              const float* __restrict__ s1,
                                              const float* __restrict__ s2,
                                              const float* __restrict__ s3,
                                              f16* __restrict__ dst) {
    const float* src = (blockIdx.y == 0) ? s0 : (blockIdx.y == 1) ? s1 : (blockIdx.y == 2) ? s2 : s3;
    f16* d = dst + (size_t)blockIdx.y * (1u << 20);
    int i = (blockIdx.x * 256 + threadIdx.x) * 8;
    float4 a = *(const float4*)(src + i);
    float4 b = *(const float4*)(src + i + 4);
    f16x8 o;
    o[0] = (f16)a.x; o[1] = (f16)a.y; o[2] = (f16)a.z; o[3] = (f16)a.w;
    o[4] = (f16)b.x; o[5] = (f16)b.y; o[6] = (f16)b.z; o[7] = (f16)b.w;
    *(f16x8*)(d + i) = o;
}

__global__ __launch_bounds__(256) void cvt_x(const float* __restrict__ src, f16* __restrict__ dst) {
    int i = (blockIdx.x * 256 + threadIdx.x) * 8;
    float4 a = *(const float4*)(src + i);
    float4 b = *(const float4*)(src + i + 4);
    f16x8 o;
    o[0] = (f16)a.x; o[1] = (f16)a.y; o[2] = (f16)a.z; o[3] = (f16)a.w;
    o[4] = (f16)b.x; o[5] = (f16)b.y; o[6] = (f16)b.z; o[7] = (f16)b.w;
    *(f16x8*)(dst + i) = o;
}

// C[M,N] = (A[M,K] * Bw[N,K]^T) * oscale.  BM=128 BN=64 BK=64, 4 waves (2x2), wave tile 64x32.
// m97 pattern: linear LDS + global_load_lds(16B).
template <int MODE>
__global__ __launch_bounds__(256, 2) void gemm_bt(const f16* __restrict__ A,
                                                  const f16* __restrict__ Bw,
                                                  f16* __restrict__ Co,
                                                  float* __restrict__ Cf,
                                                  const float* __restrict__ bias,
                                                  float oscale,
                                                  int M, int N, int K) {
    __shared__ __attribute__((aligned(16))) f16 As[128 * 64];
    __shared__ __attribute__((aligned(16))) f16 Bs[64 * 64];
    const int tid = threadIdx.x;
    const int lane = tid & 63;
    const int w = tid >> 6;
    const int l15 = lane & 15, l4 = lane >> 4;
    const int wr = (w >> 1) * 64, wc = (w & 1) * 32;
    // bijective XCD swizzle (nwg multiple of 8)
    const int nwg = gridDim.x * gridDim.y;
    const int f = blockIdx.y * gridDim.x + blockIdx.x;
    const int g = (f & 7) * (nwg >> 3) + (f >> 3);
    const int row0 = (g / gridDim.x) * 128;
    const int col0 = (g % gridDim.x) * 64;

    const int sr8 = lane >> 3;       // 0..7 row within 8-row group
    const int sc8 = (lane & 7) * 8;  // f16 col (16B chunk)
    f32x4 acc[4][2] = {};

    for (int kt = 0; kt < K; kt += 64) {
        __syncthreads();
        // A: wave w stages rows w*32 .. w*32+31 (4 x 1KB loads)
#pragma unroll
        for (int t = 0; t < 4; ++t) {
            int ra = w * 32 + t * 8 + sr8;
            stage16(&A[(size_t)(row0 + ra) * K + kt + sc8], &As[(w * 32 + t * 8) * 64]);
        }
        // B: wave w stages rows w*16 .. w*16+15 (2 x 1KB loads)
#pragma unroll
        for (int t = 0; t < 2; ++t) {
            int rb = w * 16 + t * 8 + sr8;
            stage16(&Bw[(size_t)(col0 + rb) * K + kt + sc8], &Bs[(w * 16 + t * 8) * 64]);
        }
        __syncthreads();
#pragma unroll
        for (int ks = 0; ks < 2; ++ks) {
            f16x8 af[4], bf[2];
#pragma unroll
            for (int m = 0; m < 4; ++m)
                af[m] = *(const f16x8*)&As[(wr + m * 16 + l15) * 64 + ks * 32 + l4 * 8];
#pragma unroll
            for (int n = 0; n < 2; ++n)
                bf[n] = *(const f16x8*)&Bs[(wc + n * 16 + l15) * 64 + ks * 32 + l4 * 8];
#pragma unroll
            for (int m = 0; m < 4; ++m)
#pragma unroll
                for (int n = 0; n < 2; ++n) acc[m][n] = MFMA16(af[m], bf[n], acc[m][n]);
        }
    }

#pragma unroll
    for (int m = 0; m < 4; ++m)
#pragma unroll
        for (int n = 0; n < 2; ++n)
#pragma unroll
            for (int r = 0; r < 4; ++r) {
                int rr = row0 + wr + m * 16 + l4 * 4 + r;
                int cc = col0 + wc + n * 16 + l15;
                if (MODE == 0)
                    Co[(size_t)rr * N + cc] = (f16)(acc[m][n][r] * oscale);
                else
                    Cf[(size_t)rr * N + cc] = acc[m][n][r] + bias[cc];
            }
}

// q2c2[(b*16+h)*1024+c] = sum(qs^2)/(4*C2) ; k2c2[...] = sum(k^2)*C2
__global__ __launch_bounds__(256) void norms(const f16* __restrict__ qsb,
                                             const f16* __restrict__ kbb,
                                             float* __restrict__ q2o,
                                             float* __restrict__ k2o) {
    const int idx = blockIdx.x * 256 + threadIdx.x;
    const int h = idx >> 12, token = idx & 4095;
    const int side = blockIdx.y;
    const f16* src = side ? kbb : qsb;
    const float scale = side ? (float)C2d : (float)(1.0 / (4.0 * C2d));
    const f16* p = src + (size_t)token * 1024 + h * 64;
    float s = 0.f;
#pragma unroll
    for (int j = 0; j < 8; ++j) {
        f16x8 v = *(const f16x8*)(p + j * 8);
#if __has_builtin(__builtin_amdgcn_fdot2)
#pragma unroll
        for (int t = 0; t < 4; ++t) {
            f16x2 pr = {v[2 * t], v[2 * t + 1]};
            s = __builtin_amdgcn_fdot2(pr, pr, s, false);
        }
#else
#pragma unroll
        for (int t = 0; t < 8; ++t) {
            float x = (float)v[t];
            s += x * x;
        }
#endif
    }
    float* dst = side ? k2o : q2o;
    dst[(size_t)((token >> 10) * 16 + h) * 1024 + (token & 1023)] = s * scale;
}

// v (4096 tokens x 1024) -> vT[b*16+h][dh=64][c=1024]
__global__ __launch_bounds__(256) void transpose_v(const f16* __restrict__ v, f16* __restrict__ vT) {
    __shared__ __attribute__((aligned(16))) f16 T[64][72];
    const int bh = blockIdx.y;
    const int b = bh >> 4, h = bh & 15;
    const int ct = blockIdx.x * 64;
    const int tid = threadIdx.x;
    const int cl = tid >> 3, d0 = (tid & 7) * 8;
#pragma unroll
    for (int i = 0; i < 2; ++i) {
        int c = cl + i * 32;
        *(f16x8*)&T[c][d0] = *(const f16x8*)&v[(size_t)(b * 1024 + ct + c) * 1024 + h * 64 + d0];
    }
    __syncthreads();
    const int dl = tid >> 3, c0 = (tid & 7) * 8;
#pragma unroll
    for (int i = 0; i < 2; ++i) {
        int d = dl + i * 32;
        f16x8 o;
#pragma unroll
        for (int j = 0; j < 8; ++j) o[j] = T[c0 + j][d];
        *(f16x8*)&vT[(size_t)(bh * 64 + d) * 1024 + ct + c0] = o;
    }
}

// Distance attention. grid (8,64): 128 q-rows/block, 4 waves x 32 rows.
// V in LDS; T14 reg-prefetch of next K/V/k2 tile; same-bh blocks pinned to one XCD.
__global__ __launch_bounds__(256, 2) void attn(const f16* __restrict__ qs,
                                               const f16* __restrict__ kb,
                                               const f16* __restrict__ vT,
                                               const float* __restrict__ q2c2,
                                               const float* __restrict__ k2c2,
                                               f16* __restrict__ out) {
    __shared__ __attribute__((aligned(16))) f16 Ks[128 * 72];   // padded: conflict-free reads
    __shared__ __attribute__((aligned(16))) f16 Vs[64 * 136];   // vT tile, padded
    __shared__ __attribute__((aligned(16))) f16 Ps[128 * 136];
    __shared__ float k2tile[128];
    const int tid = threadIdx.x;
    const int lane = tid & 63;
    const int w = tid >> 6;
    const int l15 = lane & 15, l4 = lane >> 4;
    // XCD remap: blocks of one bh -> same XCD (dispatch round-robins flat id % 8)
    const int fid = blockIdx.y * 8 + blockIdx.x;
    const int qt = (fid >> 3) & 7;
    const int bh = (fid & 7) * 8 + (fid >> 6);
    const int b = bh >> 4, h = bh & 15;
    const int wq = w * 32;
    const int hcol = h * 64;
    const int qrow0 = b * 1024 + qt * 128;
    const f16* vTh = vT + (size_t)bh * 64 * 1024;

    const int sr = tid >> 3, sc0 = (tid & 7) * 8;    // K staging: rows sr+i*32
    const int vr = tid >> 4, vc0 = (tid & 15) * 8;   // V staging: rows vr+j*16

    // Q frags (rows wq+m*16+l15), pre-scaled by -2*C2; q2*C2 at D-layout rows
    f16x8 aq[2][2];
#pragma unroll
    for (int m = 0; m < 2; ++m)
#pragma unroll
        for (int ks = 0; ks < 2; ++ks)
            aq[m][ks] = *(const f16x8*)&qs[(size_t)(qrow0 + wq + m * 16 + l15) * 1024 + hcol + ks * 32 + l4 * 8];
    float q2r[2][4];
#pragma unroll
    for (int m = 0; m < 2; ++m)
#pragma unroll
        for (int r = 0; r < 4; ++r)
            q2r[m][r] = q2c2[(size_t)bh * 1024 + qt * 128 + wq + m * 16 + l4 * 4 + r];

    f32x4 accv[2][4] = {};
    float den[2][4] = {{0.f, 0.f, 0.f, 0.f}, {0.f, 0.f, 0.f, 0.f}};
    const int rsw = (l15 >> 2) << 4;  // Ps read-side swizzle

    f16x8 kreg[4], vreg[4];
    float k2reg = 0.f;
#define ISSUE_LOADS(KT)                                                                                      \
    {                                                                                                        \
        _Pragma("unroll") for (int i = 0; i < 4; ++i)                                                        \
            kreg[i] = *(const f16x8*)&kb[(size_t)(b * 1024 + (KT) * 128 + sr + i * 32) * 1024 + hcol + sc0]; \
        _Pragma("unroll") for (int j = 0; j < 4; ++j)                                                        \
            vreg[j] = *(const f16x8*)&vTh[(size_t)(vr + j * 16) * 1024 + (KT) * 128 + vc0];                  \
        k2reg = (tid < 128) ? k2c2[(size_t)bh * 1024 + (KT) * 128 + tid] : 0.f;                              \
    }

    ISSUE_LOADS(0)

    for (int kt = 0; kt < 8; ++kt) {
        __syncthreads();  // prev-tile readers done
#pragma unroll
        for (int i = 0; i < 4; ++i) *(f16x8*)&Ks[(sr + i * 32) * 72 + sc0] = kreg[i];
#pragma unroll
        for (int j = 0; j < 4; ++j) *(f16x8*)&Vs[(vr + j * 16) * 136 + vc0] = vreg[j];
        if (tid < 128) k2tile[tid] = k2reg;
        __syncthreads();
        if (kt < 7) ISSUE_LOADS(kt + 1)  // prefetch: latency hides under compute below

        // S'' = (q2+k2)*C2 - 2*C2*qk via MFMA C-init; p = exp2(sqrt(relu(S'')))
#pragma unroll
        for (int n = 0; n < 8; ++n) {
            f16x8 bk0 = *(const f16x8*)&Ks[(n * 16 + l15) * 72 + l4 * 8];
            f16x8 bk1 = *(const f16x8*)&Ks[(n * 16 + l15) * 72 + 32 + l4 * 8];
            float k2v = k2tile[n * 16 + l15];
#pragma unroll
            for (int m = 0; m < 2; ++m) {
                f32x4 c0;
#pragma unroll
                for (int r = 0; r < 4; ++r) c0[r] = q2r[m][r] + k2v;
                f32x4 sfr = MFMA16(aq[m][0], bk0, c0);
                sfr = MFMA16(aq[m][1], bk1, sfr);
#pragma unroll
                for (int r = 0; r < 4; ++r) {
                    float p = EXP2F(SQRTF(fmaxf(sfr[r], 0.f)));
                    den[m][r] += p;
                    Ps[(wq + m * 16 + l4 * 4 + r) * 136 + ((n * 16 + l15) ^ (l4 << 4))] = (f16)p;
                }
            }
        }

        // PV (P rows wave-private; no barrier)
        f16x8 ap[2][4];
#pragma unroll
        for (int m = 0; m < 2; ++m)
#pragma unroll
            for (int kk = 0; kk < 4; ++kk)
                ap[m][kk] = *(const f16x8*)&Ps[(wq + m * 16 + l15) * 136 + ((kk * 32 + l4 * 8) ^ rsw)];
#pragma unroll
        for (int n2 = 0; n2 < 4; ++n2) {
            f16x8 bv[4];
#pragma unroll
            for (int kk = 0; kk < 4; ++kk)
                bv[kk] = *(const f16x8*)&Vs[(n2 * 16 + l15) * 136 + kk * 32 + l4 * 8];
#pragma unroll
            for (int m = 0; m < 2; ++m)
#pragma unroll
                for (int kk = 0; kk < 4; ++kk) accv[m][n2] = MFMA16(ap[m][kk], bv[kk], accv[m][n2]);
        }
    }

#pragma unroll
    for (int m = 0; m < 2; ++m)
#pragma unroll
        for (int r = 0; r < 4; ++r) {
            float d = den[m][r];
            d += __shfl_xor(d, 1);
            d += __shfl_xor(d, 2);
            d += __shfl_xor(d, 4);
            d += __shfl_xor(d, 8);
            den[m][r] = 1.0f / d;
        }
#pragma unroll
    for (int m = 0; m < 2; ++m)
#pragma unroll
        for (int n2 = 0; n2 < 4; ++n2)
#pragma unroll
            for (int r = 0; r < 4; ++r)
                out[(size_t)(qrow0 + wq + m * 16 + l4 * 4 + r) * 1024 + hcol + n2 * 16 + l15] =
                    (f16)(accv[m][n2][r] * den[m][r]);
}

extern "C" void kernel_launch(void* const* d_in, const int* in_sizes, int n_in,
                              void* d_out, int out_size, void* d_ws, size_t ws_size,
                              hipStream_t stream) {
    const float* Xq = (const float*)d_in[0];
    const float* Xk = (const float*)d_in[1];
    const float* Xv = (const float*)d_in[2];
    const float* Wq = (const float*)d_in[3];
    const float* Wk = (const float*)d_in[4];
    const float* Wv = (const float*)d_in[5];
    const float* Wp = (const float*)d_in[6];
    const float* bp = (const float*)d_in[7];
    float* out = (float*)d_out;

    char* ws = (char*)d_ws;
    f16* W16 = (f16*)(ws);
    f16* Xbuf = (f16*)(ws + (8ull << 20));
    f16* qb = (f16*)(ws + (16ull << 20));
    f16* kb = (f16*)(ws + (24ull << 20));
    f16* vb = (f16*)(ws + (32ull << 20));
    f16* vTb = (f16*)(ws + (40ull << 20));
    // q2/k2 overlay the Wq16 slot (dead after q/k gemms; rewritten each launch)
    float* q2c2 = (float*)(ws);
    float* k2c2 = (float*)(ws + (256ull << 10));

    const int M = 4096, N = 1024, K = 1024;
    dim3 gg(N / 64, M / 128);  // 16 x 32 = 512 blocks
    const float qscale = (float)(-2.0 * C2d);

    cvt_w4<<<dim3(512, 4), 256, 0, stream>>>(Wq, Wk, Wv, Wp, W16);

    cvt_x<<<2048, 256, 0, stream>>>(Xq, Xbuf);
    gemm_bt<0><<<gg, 256, 0, stream>>>(Xbuf, W16 + 0 * (1u << 20), qb, nullptr, nullptr, qscale, M, N, K);
    cvt_x<<<2048, 256, 0, stream>>>(Xk, Xbuf);
    gemm_bt<0><<<gg, 256, 0, stream>>>(Xbuf, W16 + 1 * (1u << 20), kb, nullptr, nullptr, 1.0f, M, N, K);

    norms<<<dim3(256, 2), 256, 0, stream>>>(qb, kb, q2c2, k2c2);

    cvt_x<<<2048, 256, 0, stream>>>(Xv, Xbuf);
    gemm_bt<0><<<gg, 256, 0, stream>>>(Xbuf, W16 + 2 * (1u << 20), vb, nullptr, nullptr, 1.0f, M, N, K);

    transpose_v<<<dim3(16, 64), 256, 0, stream>>>(vb, vTb);
    attn<<<dim3(8, 64), 256, 0, stream>>>(qb, kb, vTb, q2c2, k2c2, Xbuf);

    gemm_bt<1><<<gg, 256, 0, stream>>>(Xbuf, W16 + 3 * (1u << 20), nullptr, out, bp, 1.0f, M, N, K);
}

// Round 5
// 130.774 us; speedup vs baseline: 1.5955x; 1.2086x over previous
//
#include <hip/hip_runtime.h>

// MultiHeadAttentionForViTDiscriminator: B=4, C=1024, D=1024, H=16, DH=64
// R5: re-anchor. attn = R3-proven 16x16x32 core + XOR bank-swizzled Ks/Vs
//     (pad removed; pad gave 8-way conflicts on b128 frag reads).
//     Keep R4 fusions: single cvt kernel, fused q+k GEMM with norms-from-ROUNDED
//     values in the epilogue (bit-identical to R3 norm numerics), direct vT GEMM.
// Workspace (48 MB):
//   [0,8M)  W16 (Wq,Wk,Wv,Wp f16, contiguous 4M f16)
//   [8,32M) X16: Xq16,Xk16,Xv16; Xq16 slot -> vT after qk-gemm,
//           Xk16 slot -> attn_out after vT-gemm
//   [32,40M) qb (pre-scaled by -2*C2)   [40,48M) kb
//   norms q2c2/k2c2 (2 x 256KB f32) live in d_out's head (dead before final GEMM).

typedef _Float16 f16;
typedef __attribute__((ext_vector_type(8))) _Float16 f16x8;
typedef __attribute__((ext_vector_type(4))) float f32x4;

#define MFMA16(a, b, c) __builtin_amdgcn_mfma_f32_16x16x32_f16((a), (b), (c), 0, 0, 0)

constexpr double LOG2E = 1.4426950408889634;
constexpr double C2d = 0.015625 * LOG2E * LOG2E;  // (DH^-0.5 * log2e)^2

#if __has_builtin(__builtin_amdgcn_exp2f)
#define EXP2F(x) __builtin_amdgcn_exp2f(x)
#else
#define EXP2F(x) exp2f(x)
#endif
#if __has_builtin(__builtin_amdgcn_sqrtf)
#define SQRTF(x) __builtin_amdgcn_sqrtf(x)
#else
#define SQRTF(x) sqrtf(x)
#endif

// Async global->LDS, 16B per lane (dest = wave-uniform base + lane*16).
__device__ __forceinline__ void stage16(const f16* g, f16* lds_base_uniform) {
#if __has_builtin(__builtin_amdgcn_global_load_lds)
    __builtin_amdgcn_global_load_lds((const __attribute__((address_space(1))) void*)g,
                                     (__attribute__((address_space(3))) void*)lds_base_uniform,
                                     16, 0, 0);
#else
    const int lane = threadIdx.x & 63;
    *(f16x8*)(lds_base_uniform + lane * 8) = *(const f16x8*)g;
#endif
}

// One conversion kernel for all fp32->fp16 inputs. 8192 blocks x 2048 elems = 16M.
__global__ __launch_bounds__(256) void cvt_all(const float* __restrict__ Xq,
                                               const float* __restrict__ Xk,
                                               const float* __restrict__ Xv,
                                               const float* __restrict__ Wq,
                                               const float* __restrict__ Wk,
                                               const float* __restrict__ Wv,
                                               const float* __restrict__ Wp,
                                               f16* __restrict__ W16,
                                               f16* __restrict__ X16) {
    const size_t idx = (size_t)blockIdx.x * 2048 + threadIdx.x * 8;
    const size_t M4 = 4ull << 20, M1 = 1ull << 20;
    const float* s;
    f16* d;
    if (idx < 3 * M4) {  // X region (12M)
        if (idx < M4) s = Xq + idx;
        else if (idx < 2 * M4) s = Xk + (idx - M4);
        else s = Xv + (idx - 2 * M4);
        d = X16 + idx;
    } else {  // W region (4M)
        size_t wi = idx - 3 * M4;
        if (wi < M1) s = Wq + wi;
        else if (wi < 2 * M1) s = Wk + (wi - M1);
        else if (wi < 3 * M1) s = Wv + (wi - 2 * M1);
        else s = Wp + (wi - 3 * M1);
        d = W16 + wi;
    }
    float4 a = *(const float4*)s;
    float4 b = *(const float4*)(s + 4);
    f16x8 o;
    o[0] = (f16)a.x; o[1] = (f16)a.y; o[2] = (f16)a.z; o[3] = (f16)a.w;
    o[4] = (f16)b.x; o[5] = (f16)b.y; o[6] = (f16)b.z; o[7] = (f16)b.w;
    *(f16x8*)d = o;
}

// C[M,N] = (A[M,K] * Bw[N,K]^T) * osc.  BM=128 BN=64 BK=64; 4 waves, wave tile 32x64.
// NORMS: emit per-row head-norms from the ROUNDED stored values:
//   nrm[(b*16+h)*1024+c] = sum_over_head((float)(f16)(acc*osc))^2 * nscale.
// F32OUT: f32 out + bias.  blockIdx.z offsets A/Bw/Co/nrm (fused q/k launch).
template <bool NORMS, bool F32OUT>
__global__ __launch_bounds__(256, 2) void gemm_bt(const f16* __restrict__ A,
                                                  const f16* __restrict__ Bw,
                                                  f16* __restrict__ Co,
                                                  float* __restrict__ Cf,
                                                  const float* __restrict__ bias,
                                                  float* __restrict__ nrm,
                                                  float osc0, float osc1,
                                                  float ns0, float ns1,
                                                  int M, int N, int K) {
    __shared__ __attribute__((aligned(16))) f16 As[128 * 64];
    __shared__ __attribute__((aligned(16))) f16 Bs[64 * 64];
    const int tid = threadIdx.x;
    const int lane = tid & 63;
    const int w = tid >> 6;
    const int l15 = lane & 15, l4 = lane >> 4;
    const int z = blockIdx.z;
    A += (size_t)z * (4u << 20);
    Bw += (size_t)z * (1u << 20);
    Co += (size_t)z * (4u << 20);
    if (NORMS) nrm += (size_t)z * 65536;
    const float osc = z ? osc1 : osc0;
    const float nscale = z ? ns1 : ns0;
    const int wr = w * 32;
    // bijective XCD swizzle (nwg multiple of 8)
    const int nwg = gridDim.x * gridDim.y;
    const int f = blockIdx.y * gridDim.x + blockIdx.x;
    const int g = (f & 7) * (nwg >> 3) + (f >> 3);
    const int row0 = (g / gridDim.x) * 128;
    const int col0 = (g % gridDim.x) * 64;

    const int sr8 = lane >> 3;
    const int sc8 = (lane & 7) * 8;
    f32x4 acc[2][4] = {};

    for (int kt = 0; kt < K; kt += 64) {
        __syncthreads();
#pragma unroll
        for (int t = 0; t < 4; ++t)
            stage16(&A[(size_t)(row0 + w * 32 + t * 8 + sr8) * K + kt + sc8], &As[(w * 32 + t * 8) * 64]);
#pragma unroll
        for (int t = 0; t < 2; ++t)
            stage16(&Bw[(size_t)(col0 + w * 16 + t * 8 + sr8) * K + kt + sc8], &Bs[(w * 16 + t * 8) * 64]);
        __syncthreads();
#pragma unroll
        for (int ks = 0; ks < 2; ++ks) {
            f16x8 af[2], bf[4];
#pragma unroll
            for (int m = 0; m < 2; ++m)
                af[m] = *(const f16x8*)&As[(wr + m * 16 + l15) * 64 + ks * 32 + l4 * 8];
#pragma unroll
            for (int n = 0; n < 4; ++n)
                bf[n] = *(const f16x8*)&Bs[(n * 16 + l15) * 64 + ks * 32 + l4 * 8];
#pragma unroll
            for (int m = 0; m < 2; ++m)
#pragma unroll
                for (int n = 0; n < 4; ++n) acc[m][n] = MFMA16(af[m], bf[n], acc[m][n]);
        }
    }

    if (NORMS) {
        // norm over the 64 head-cols of the ROUNDED stored values (R3-exact numerics)
        const int h = col0 >> 6;
#pragma unroll
        for (int m = 0; m < 2; ++m)
#pragma unroll
            for (int r = 0; r < 4; ++r) {
                float s = 0.f;
#pragma unroll
                for (int n = 0; n < 4; ++n) {
                    float v = (float)(f16)(acc[m][n][r] * osc);
                    s += v * v;
                }
                s += __shfl_xor(s, 1);
                s += __shfl_xor(s, 2);
                s += __shfl_xor(s, 4);
                s += __shfl_xor(s, 8);
                if (l15 == 0) {
                    int row = row0 + wr + m * 16 + l4 * 4 + r;
                    nrm[(size_t)((row >> 10) * 16 + h) * 1024 + (row & 1023)] = s * nscale;
                }
            }
    }

#pragma unroll
    for (int m = 0; m < 2; ++m)
#pragma unroll
        for (int n = 0; n < 4; ++n)
#pragma unroll
            for (int r = 0; r < 4; ++r) {
                int rr = row0 + wr + m * 16 + l4 * 4 + r;
                int cc = col0 + n * 16 + l15;
                if (F32OUT)
                    Cf[(size_t)rr * N + cc] = acc[m][n][r] + bias[cc];
                else
                    Co[(size_t)rr * N + cc] = (f16)(acc[m][n][r] * osc);
            }
}

// Distance attention. grid (8,64): 128 q-rows/block, 4 waves x 32 rows.
// R3-proven 16x16x32 core; Ks/Vs XOR-swizzled (unpadded); V in LDS; reg-prefetch;
// same-bh blocks pinned to one XCD.
__global__ __launch_bounds__(256, 2) void attn(const f16* __restrict__ qs,
                                               const f16* __restrict__ kb,
                                               const f16* __restrict__ vT,
                                               const float* __restrict__ q2c2,
                                               const float* __restrict__ k2c2,
                                               f16* __restrict__ out) {
    __shared__ __attribute__((aligned(16))) f16 Ks[128 * 64];   // XOR-swizzled
    __shared__ __attribute__((aligned(16))) f16 Vs[64 * 128];   // XOR-swizzled
    __shared__ __attribute__((aligned(16))) f16 Ps[128 * 136];  // R3 pad+swizzle
    __shared__ float k2tile[128];
    const int tid = threadIdx.x;
    const int lane = tid & 63;
    const int w = tid >> 6;
    const int l15 = lane & 15, l4 = lane >> 4;
    // XCD remap: 8 bh per XCD -> K/V slices L2-resident
    const int fid = blockIdx.y * 8 + blockIdx.x;
    const int qt = (fid >> 3) & 7;
    const int bh = (fid & 7) * 8 + (fid >> 6);
    const int b = bh >> 4, h = bh & 15;
    const int wq = w * 32;
    const int hcol = h * 64;
    const int qrow0 = b * 1024 + qt * 128;
    const f16* vTh = vT + (size_t)hcol * 4096 + b * 1024;  // vT[d=1024][tok=4096]

    const int sr = tid >> 3, sc0 = (tid & 7) * 8;   // K staging (rows sr+i*32)
    const int ksw = (sr & 7) << 3;
    const int vr = tid >> 4, vc0 = (tid & 15) * 8;  // V staging (rows vr+j*16)
    const int vsw = (vr & 7) << 3;
    const int fsw = (l15 & 7) << 3;                 // fragment-read swizzle (row&7 = l15&7)

    // Q frags (rows wq+m*16+l15), pre-scaled by -2*C2; q2*C2 at D-layout rows
    f16x8 aq[2][2];
#pragma unroll
    for (int m = 0; m < 2; ++m)
#pragma unroll
        for (int ks = 0; ks < 2; ++ks)
            aq[m][ks] = *(const f16x8*)&qs[(size_t)(qrow0 + wq + m * 16 + l15) * 1024 + hcol + ks * 32 + l4 * 8];
    float q2r[2][4];
#pragma unroll
    for (int m = 0; m < 2; ++m)
#pragma unroll
        for (int r = 0; r < 4; ++r)
            q2r[m][r] = q2c2[(size_t)bh * 1024 + qt * 128 + wq + m * 16 + l4 * 4 + r];

    f32x4 accv[2][4] = {};
    float den[2][4] = {{0.f, 0.f, 0.f, 0.f}, {0.f, 0.f, 0.f, 0.f}};
    const int rsw = (l15 >> 2) << 4;  // Ps read-side swizzle

    f16x8 kreg[4], vreg[4];
    float k2reg = 0.f;
#define ISSUE_LOADS(KT)                                                                                      \
    {                                                                                                        \
        _Pragma("unroll") for (int i = 0; i < 4; ++i)                                                        \
            kreg[i] = *(const f16x8*)&kb[(size_t)(b * 1024 + (KT) * 128 + sr + i * 32) * 1024 + hcol + sc0]; \
        _Pragma("unroll") for (int j = 0; j < 4; ++j)                                                        \
            vreg[j] = *(const f16x8*)&vTh[(size_t)(vr + j * 16) * 4096 + (KT) * 128 + vc0];                  \
        k2reg = (tid < 128) ? k2c2[(size_t)bh * 1024 + (KT) * 128 + tid] : 0.f;                              \
    }

    ISSUE_LOADS(0)

    for (int kt = 0; kt < 8; ++kt) {
        __syncthreads();  // prev-tile readers done
#pragma unroll
        for (int i = 0; i < 4; ++i) *(f16x8*)&Ks[(sr + i * 32) * 64 + (sc0 ^ ksw)] = kreg[i];
#pragma unroll
        for (int j = 0; j < 4; ++j) *(f16x8*)&Vs[(vr + j * 16) * 128 + (vc0 ^ vsw)] = vreg[j];
        if (tid < 128) k2tile[tid] = k2reg;
        __syncthreads();
        if (kt < 7) ISSUE_LOADS(kt + 1)  // prefetch hides under compute

        // S'' = (q2+k2)*C2 - 2*C2*qk via MFMA C-init; p = exp2(sqrt(relu(S'')))
#pragma unroll
        for (int n = 0; n < 8; ++n) {
            f16x8 bk0 = *(const f16x8*)&Ks[(n * 16 + l15) * 64 + ((l4 * 8) ^ fsw)];
            f16x8 bk1 = *(const f16x8*)&Ks[(n * 16 + l15) * 64 + ((32 + l4 * 8) ^ fsw)];
            float k2v = k2tile[n * 16 + l15];
#pragma unroll
            for (int m = 0; m < 2; ++m) {
                f32x4 c0;
#pragma unroll
                for (int r = 0; r < 4; ++r) c0[r] = q2r[m][r] + k2v;
                f32x4 sfr = MFMA16(aq[m][0], bk0, c0);
                sfr = MFMA16(aq[m][1], bk1, sfr);
#pragma unroll
                for (int r = 0; r < 4; ++r) {
                    float p = EXP2F(SQRTF(fmaxf(sfr[r], 0.f)));
                    den[m][r] += p;
                    Ps[(wq + m * 16 + l4 * 4 + r) * 136 + ((n * 16 + l15) ^ (l4 << 4))] = (f16)p;
                }
            }
        }

        // PV (P rows wave-private; no barrier)
        f16x8 ap[2][4];
#pragma unroll
        for (int m = 0; m < 2; ++m)
#pragma unroll
            for (int kk = 0; kk < 4; ++kk)
                ap[m][kk] = *(const f16x8*)&Ps[(wq + m * 16 + l15) * 136 + ((kk * 32 + l4 * 8) ^ rsw)];
#pragma unroll
        for (int n2 = 0; n2 < 4; ++n2) {
            f16x8 bv[4];
#pragma unroll
            for (int kk = 0; kk < 4; ++kk)
                bv[kk] = *(const f16x8*)&Vs[(n2 * 16 + l15) * 128 + ((kk * 32 + l4 * 8) ^ fsw)];
#pragma unroll
            for (int m = 0; m < 2; ++m)
#pragma unroll
                for (int kk = 0; kk < 4; ++kk) accv[m][n2] = MFMA16(ap[m][kk], bv[kk], accv[m][n2]);
        }
    }

#pragma unroll
    for (int m = 0; m < 2; ++m)
#pragma unroll
        for (int r = 0; r < 4; ++r) {
            float d = den[m][r];
            d += __shfl_xor(d, 1);
            d += __shfl_xor(d, 2);
            d += __shfl_xor(d, 4);
            d += __shfl_xor(d, 8);
            den[m][r] = 1.0f / d;
        }
#pragma unroll
    for (int m = 0; m < 2; ++m)
#pragma unroll
        for (int n2 = 0; n2 < 4; ++n2)
#pragma unroll
            for (int r = 0; r < 4; ++r)
                out[(size_t)(qrow0 + wq + m * 16 + l4 * 4 + r) * 1024 + hcol + n2 * 16 + l15] =
                    (f16)(accv[m][n2][r] * den[m][r]);
}

extern "C" void kernel_launch(void* const* d_in, const int* in_sizes, int n_in,
                              void* d_out, int out_size, void* d_ws, size_t ws_size,
                              hipStream_t stream) {
    const float* Xq = (const float*)d_in[0];
    const float* Xk = (const float*)d_in[1];
    const float* Xv = (const float*)d_in[2];
    const float* Wq = (const float*)d_in[3];
    const float* Wk = (const float*)d_in[4];
    const float* Wv = (const float*)d_in[5];
    const float* Wp = (const float*)d_in[6];
    const float* bp = (const float*)d_in[7];
    float* out = (float*)d_out;

    char* ws = (char*)d_ws;
    f16* W16 = (f16*)(ws);                      // 4M f16
    f16* X16 = (f16*)(ws + (8ull << 20));       // 12M f16: Xq16|Xk16|Xv16
    f16* vTb = (f16*)(ws + (8ull << 20));       // overlays Xq16 (dead after qk-gemm)
    f16* attnout = (f16*)(ws + (16ull << 20));  // overlays Xk16 (dead after vT-gemm)
    f16* Xv16 = (f16*)(ws + (24ull << 20));
    f16* qb = (f16*)(ws + (32ull << 20));       // qk out base (z-stride 4M f16)
    f16* kb = (f16*)(ws + (40ull << 20));
    // norms scratch in d_out head; written each launch before use, overwritten by final GEMM
    float* q2c2 = out;
    float* k2c2 = out + 65536;

    const float qsc = (float)(-2.0 * C2d);
    const float ns_q = (float)(1.0 / (4.0 * C2d));  // (q*-2C2)^2 * ns_q = C2*q^2
    const float ns_k = (float)C2d;

    cvt_all<<<8192, 256, 0, stream>>>(Xq, Xk, Xv, Wq, Wk, Wv, Wp, W16, X16);

    // fused q+k projection (z=0: q with -2*C2 prescale, z=1: k), norms in epilogue
    gemm_bt<true, false><<<dim3(16, 32, 2), 256, 0, stream>>>(
        X16, W16, qb, nullptr, nullptr, q2c2, qsc, 1.0f, ns_q, ns_k, 4096, 1024, 1024);

    // vT = Wv * Xv^T : [1024 d][4096 tok]
    gemm_bt<false, false><<<dim3(64, 8), 256, 0, stream>>>(
        W16 + 2 * (1u << 20), Xv16, vTb, nullptr, nullptr, nullptr, 1.0f, 1.0f, 0.f, 0.f, 1024, 4096, 1024);

    attn<<<dim3(8, 64), 256, 0, stream>>>(qb, kb, vTb, q2c2, k2c2, attnout);

    gemm_bt<false, true><<<dim3(16, 32), 256, 0, stream>>>(
        attnout, W16 + 3 * (1u << 20), nullptr, out, bp, nullptr, 1.0f, 1.0f, 0.f, 0.f, 4096, 1024, 1024);
}